// Round 11
// baseline (496.178 us; speedup 1.0000x reference)
//
#include <hip/hip_runtime.h>
#include <hip/hip_bf16.h>

#define EPSV 1e-5f

typedef __attribute__((ext_vector_type(8))) short bf16x8;
typedef __attribute__((ext_vector_type(16))) float f32x16;

static __device__ __forceinline__ short f2bf(float f) {
    __hip_bfloat16 b = __float2bfloat16(f);
    return __builtin_bit_cast(short, b);
}
static __device__ __forceinline__ float bf2f(short s) {
    unsigned u = ((unsigned)(unsigned short)s) << 16;
    return __builtin_bit_cast(float, u);
}

// Fused role-split: blocks [0,EBL) = edge MLP; blocks [EBL, EBL+65) = w2->w2a repack.
// w2a slab layout: [(c*2+rowg)*512 + l*8 + j] = bf16(w2[h][i*64+o]),
//   o = rowg*32+(l&31), i = c*16+(l>>5)*8+j ; slab 64 = b2.
// zge[e*64 + h] = bf16(relu(b1[h] + ea@w1))
template <int CIN>
__global__ void k_edge_prep(const float* __restrict__ ea, const float* __restrict__ w1,
                            const float* __restrict__ b1, short* __restrict__ zge, int E, int EBL,
                            const float* __restrict__ w2, const float* __restrict__ b2,
                            short* __restrict__ w2a) {
    constexpr int CH = CIN / 16;
    int t = threadIdx.x;
    if ((int)blockIdx.x >= EBL) {
        int h = (int)blockIdx.x - EBL;          // 0..64
        __shared__ float sW[CIN][65];
        const float* srcp = (h < 64) ? (w2 + (size_t)h * (CIN * 64)) : b2;
        for (int f = t; f < CIN * 64; f += 256) sW[f >> 6][f & 63] = srcp[f];
        __syncthreads();
        int l = t & 63, w = t >> 6;
        short* outp = w2a + (size_t)h * (CH * 1024);
        constexpr int SEGW = (CH * 2) / 4 > 0 ? (CH * 2) / 4 : 1;
        #pragma unroll
        for (int q = 0; q < SEGW; ++q) {
            int s = w + q * 4;
            int c = s >> 1, rowg = s & 1;
            int ib = c * 16 + (l >> 5) * 8;
            int o = rowg * 32 + (l & 31);
            union { bf16x8 v; short sh[8]; } ov;
            #pragma unroll
            for (int j = 0; j < 8; ++j) ov.sh[j] = f2bf(sW[ib + j][o]);
            *reinterpret_cast<bf16x8*>(outp + s * 512 + l * 8) = ov.v;
        }
        return;
    }
    __shared__ float sEA[64][17];
    int e0 = blockIdx.x * 64;
    for (int f = t; f < 64 * 16; f += 256) {
        int e = f >> 4, i = f & 15;
        int ge = e0 + e;
        sEA[e][i] = (ge < E) ? ea[(size_t)ge * 16 + i] : 0.f;
    }
    __syncthreads();
    int lane = t & 63, w = t >> 6;
    int ge = e0 + lane;
    union { bf16x8 v[2]; short s[16]; } ov;
    #pragma unroll
    for (int hh = 0; hh < 16; ++hh) {
        int h = w * 16 + hh;
        float acc = b1[h];
        #pragma unroll
        for (int i = 0; i < 16; ++i) acc += sEA[lane][i] * w1[i * 64 + h];
        ov.s[hh] = f2bf(fmaxf(acc, 0.f));
    }
    if (ge < E) {
        short* base = zge + (size_t)ge * 64 + w * 16;
        *reinterpret_cast<bf16x8*>(base) = ov.v[0];
        *reinterpret_cast<bf16x8*>(base + 8) = ov.v[1];
    }
}

// layer-1 fused prep: agg init (root GEMM on x) + x -> bf16
__global__ void k_pre1(const float* __restrict__ x, const float* __restrict__ root,
                       const float* __restrict__ bias, short* __restrict__ xb,
                       float* __restrict__ out, int N) {
    int idx = blockIdx.x * blockDim.x + threadIdx.x;
    int n = idx >> 6, o = idx & 63;
    if (n >= N) return;
    float acc = bias[o];
    #pragma unroll
    for (int i = 0; i < 32; ++i) acc += x[(size_t)n * 32 + i] * root[i * 64 + o];
    out[(size_t)n * 64 + o] = acc;
    if (o < 32) xb[(size_t)n * 32 + o] = f2bf(x[(size_t)n * 32 + o]);
}

// MFMA msg v9: 128-edge tile, NO h-split, NO in-loop barriers, NO LDS staging of A.
// A slabs stream L2->VGPR, 3-buffer rotation, sched_barrier(0) fences enforce the
// software pipeline (2-slab lookahead). z in padded LDS (conflict-free, no scratch).
// 512 threads = 8 waves: rowg = w>>2 (o half), eg = w&3 (32-edge group).
template <int CIN>
__global__ __launch_bounds__(512, 4) void k_msg(const short* __restrict__ zge,
                                                const short* __restrict__ xb,
                                                const int* __restrict__ src,
                                                const int* __restrict__ dstv,
                                                const short* __restrict__ w2a,
                                                float* __restrict__ agg, int E) {
    constexpr int CH = CIN / 16;
    constexpr int SLAB = CH * 1024;        // shorts per h-slab
    __shared__ char smem[128 * 66 * 2] __attribute__((aligned(16)));  // sZ shorts / sT floats
    short* sZ = reinterpret_cast<short*>(smem);        // [128][66] bf16, padded
    float* sT = reinterpret_cast<float*>(smem);        // [64][66] f32 (epilogue reuse)

    int t = threadIdx.x;
    int e0 = blockIdx.x * 128;
    int lane = t & 63, w = t >> 6;
    int rowg = w >> 2;            // o half
    int eg = w & 3;               // 32-edge group
    int kg = lane >> 5, l31 = lane & 31;
    int ecol = eg * 32 + l31;     // block-local edge col
    int ge = e0 + ecol;
    int gec = min(ge, E - 1);

    // B operand: x[src(e)] fragments, fixed across all h
    int srow = src[gec];
    bf16x8 xB[CH];
    #pragma unroll
    for (int c = 0; c < CH; ++c)
        xB[c] = *reinterpret_cast<const bf16x8*>(xb + (size_t)srow * CIN + c * 16 + kg * 8);

    // z tile -> LDS: 128 edges x 64 h, rows padded to 66 shorts (bank-conflict-free reads)
    #pragma unroll
    for (int rr = 0; rr < 2; ++rr) {
        int f = rr * 512 + t;              // 1024 units: e = f>>3, seg = f&7
        int e = f >> 3, seg = f & 7;
        int gz = min(e0 + e, E - 1);
        bf16x8 zv = *reinterpret_cast<const bf16x8*>(zge + (size_t)gz * 64 + seg * 8);
        *reinterpret_cast<bf16x8*>(sZ + e * 66 + seg * 8) = zv;
    }

    f32x16 zero;
    #pragma unroll
    for (int r = 0; r < 16; ++r) zero[r] = 0.f;
    asm volatile("" : "+v"(zero));

    f32x16 acc = zero;

    const short* ap = w2a + (size_t)(rowg * 512) + lane * 8;

    bf16x8 X[CH], Y[CH], Z[CH];
    auto loadA = [&](bf16x8* B, int slab) {
        int sl = min(slab, 64);            // clamp: over-reads slab 64, never consumed
        const short* g = ap + (size_t)sl * SLAB;
        #pragma unroll
        for (int c = 0; c < CH; ++c)
            B[c] = *reinterpret_cast<const bf16x8*>(g + c * 1024);
    };
    auto consume = [&](const bf16x8* B, int ci, bool isb2) {
        f32x16 tt = __builtin_amdgcn_mfma_f32_32x32x16_bf16(B[0], xB[0], zero, 0, 0, 0);
        #pragma unroll
        for (int c = 1; c < CH; ++c)
            tt = __builtin_amdgcn_mfma_f32_32x32x16_bf16(B[c], xB[c], tt, 0, 0, 0);
        if (!isb2) {
            float zf = bf2f(sZ[ecol * 66 + ci]);
            #pragma unroll
            for (int r = 0; r < 16; ++r) acc[r] = fmaf(zf, tt[r], acc[r]);
        } else {
            #pragma unroll
            for (int r = 0; r < 16; ++r) acc[r] += tt[r];
        }
    };

    loadA(X, 0); loadA(Y, 1); loadA(Z, 2);
    __syncthreads();   // sZ ready (also covers prologue loads ordering for LDS)

    #pragma unroll 1
    for (int k = 0; k < 21; ++k) {         // slabs 0..62, 3 per iteration
        int s = 3 * k;
        consume(X, s, false);  loadA(X, s + 3);
        __builtin_amdgcn_sched_barrier(0);
        consume(Y, s + 1, false); loadA(Y, s + 4);
        __builtin_amdgcn_sched_barrier(0);
        consume(Z, s + 2, false); loadA(Z, s + 5);
        __builtin_amdgcn_sched_barrier(0);
    }
    consume(X, 63, false);                 // slab 63
    consume(Y, 64, true);                  // slab 64 = b2 (z = 1)

    __syncthreads();   // all sZ reads done before sT overwrite

    // two-pass transpose+scatter: pass p handles block-local e-cols [p*64, p*64+64)
    #pragma unroll
    for (int p = 0; p < 2; ++p) {
        if ((eg >> 1) == p) {
            #pragma unroll
            for (int r = 0; r < 16; ++r) {
                int o = (r & 3) + 8 * (r >> 2) + 4 * kg + 32 * rowg;
                sT[o * 66 + (eg & 1) * 32 + l31] = acc[r];
            }
        }
        __syncthreads();
        for (int e = w; e < 64; e += 8) {
            int geo = e0 + p * 64 + e;
            if (geo < E) {
                int d = dstv[geo];
                atomicAdd(&agg[(size_t)d * 64 + lane], sT[lane * 66 + e]);
            }
        }
        __syncthreads();
    }
}

// fused LayerNorm+ReLU -> bf16 (for next msg) AND next layer's root GEMM (agg init).
__global__ void k_ln_root(const float* __restrict__ hin, const float* __restrict__ g,
                          const float* __restrict__ b, const float* __restrict__ root,
                          const float* __restrict__ bias, short* __restrict__ xbout,
                          float* __restrict__ aggnext, int N) {
    __shared__ float sh[4][64];
    int w = threadIdx.x >> 6, lane = threadIdx.x & 63;
    int n = blockIdx.x * 4 + w;
    bool valid = n < N;
    int nc = valid ? n : (N - 1);
    float v = hin[(size_t)nc * 64 + lane];
    float s = v;
    #pragma unroll
    for (int d = 32; d > 0; d >>= 1) s += __shfl_xor(s, d, 64);
    float mean = s * (1.f / 64.f);
    float dv = v - mean;
    float s2 = dv * dv;
    #pragma unroll
    for (int d = 32; d > 0; d >>= 1) s2 += __shfl_xor(s2, d, 64);
    float var = s2 * (1.f / 64.f);
    float o = fmaxf(dv * rsqrtf(var + EPSV) * g[lane] + b[lane], 0.f);
    if (valid) xbout[(size_t)n * 64 + lane] = f2bf(o);
    sh[w][lane] = o;
    __syncthreads();
    float acc = bias[lane];
    #pragma unroll 8
    for (int i = 0; i < 64; ++i) acc = fmaf(sh[w][i], root[i * 64 + lane], acc);
    if (valid) aggnext[(size_t)n * 64 + lane] = acc;
}

// plain LayerNorm+ReLU in place (final layer)
__global__ void k_ln(float* __restrict__ h, const float* __restrict__ g, const float* __restrict__ b, int N) {
    int n = blockIdx.x * 4 + (threadIdx.x >> 6);
    int lane = threadIdx.x & 63;
    if (n >= N) return;
    float v = h[(size_t)n * 64 + lane];
    float s = v;
    #pragma unroll
    for (int d = 32; d > 0; d >>= 1) s += __shfl_xor(s, d, 64);
    float mean = s * (1.f / 64.f);
    float dv = v - mean;
    float s2 = dv * dv;
    #pragma unroll
    for (int d = 32; d > 0; d >>= 1) s2 += __shfl_xor(s2, d, 64);
    float var = s2 * (1.f / 64.f);
    h[(size_t)n * 64 + lane] = fmaxf(dv * rsqrtf(var + EPSV) * g[lane] + b[lane], 0.f);
}

// fused mean-pool (binary search on sorted batch) + MLP head; 4 waves/graph
__global__ void k_pool_head(const float* __restrict__ h, const int* __restrict__ batch,
                            const float* __restrict__ fc1w, const float* __restrict__ fc1b,
                            const float* __restrict__ fc2w, const float* __restrict__ fc2b,
                            float* __restrict__ out, int N) {
    __shared__ float part[4][64];
    __shared__ float sh[64];
    __shared__ float sh2[32];
    int g = blockIdx.x;
    int t = threadIdx.x, lane = t & 63, w = t >> 6;
    int lo = 0, hi = N;
    while (lo < hi) { int m = (lo + hi) >> 1; if (batch[m] < g) lo = m + 1; else hi = m; }
    int s0 = lo;
    hi = N;
    while (lo < hi) { int m = (lo + hi) >> 1; if (batch[m] < g + 1) lo = m + 1; else hi = m; }
    int s1 = lo;
    float s = 0.f;
    for (int n = s0 + w; n < s1; n += 4) s += h[(size_t)n * 64 + lane];
    part[w][lane] = s;
    __syncthreads();
    if (t < 64) {
        float c = fmaxf((float)(s1 - s0), 1.f);
        sh[t] = (part[0][t] + part[1][t] + part[2][t] + part[3][t]) / c;
    }
    __syncthreads();
    if (t < 32) {
        float a = fc1b[t];
        #pragma unroll
        for (int o = 0; o < 64; ++o) a += sh[o] * fc1w[o * 32 + t];
        sh2[t] = fmaxf(a, 0.f);
    }
    __syncthreads();
    if (t == 0) {
        float a = fc2b[0];
        #pragma unroll
        for (int j = 0; j < 32; ++j) a += sh2[j] * fc2w[j];
        out[g] = a;
    }
}

extern "C" void kernel_launch(void* const* d_in, const int* in_sizes, int n_in,
                              void* d_out, int out_size, void* d_ws, size_t ws_size,
                              hipStream_t stream) {
    const float* x     = (const float*)d_in[0];
    const int*   ei    = (const int*)d_in[1];
    const float* ea    = (const float*)d_in[2];
    const int*   batch = (const int*)d_in[3];
    int E = in_sizes[1] / 2;
    int N = in_sizes[3];
    int G = out_size;  // DOUT = 1
    const int* src  = ei;
    const int* dstv = ei + E;

    const float* P[24];
    for (int i = 0; i < 24; ++i) P[i] = (const float*)d_in[4 + i];
    const float* fc1w = (const float*)d_in[28];
    const float* fc1b = (const float*)d_in[29];
    const float* fc2w = (const float*)d_in[30];
    const float* fc2b = (const float*)d_in[31];

    // workspace layout
    float* hA  = (float*)d_ws;                 // N*64 f32
    float* hB  = hA + (size_t)N * 64;          // N*64 f32
    short* zge = (short*)(hB + (size_t)N * 64);// E*64 bf16 (z rows)
    short* xbA = zge + (size_t)E * 64;         // N*64 bf16
    short* xbB = xbA + (size_t)N * 64;         // N*64 bf16
    short* w2a = xbB + (size_t)N * 64;         // 65 slabs * CH*1024 bf16

    int ebl = (E + 63) / 64;
    int mbl = (E + 127) / 128;                 // 128-edge msg tiles
    int n64 = (N * 64 + 255) / 256;
    int nln = (N + 3) / 4;

    // ---- layer 1 (cin = 32) ----
    k_edge_prep<32><<<ebl + 65, 256, 0, stream>>>(ea, P[0], P[1], zge, E, ebl, P[2], P[3], w2a);
    k_pre1<<<n64, 256, 0, stream>>>(x, P[4], P[5], xbA, hA, N);
    k_msg<32><<<mbl, 512, 0, stream>>>(zge, xbA, src, dstv, w2a, hA, E);

    // ---- layer 2 (cin = 64) ----
    k_edge_prep<64><<<ebl + 65, 256, 0, stream>>>(ea, P[8], P[9], zge, E, ebl, P[10], P[11], w2a);
    k_ln_root<<<nln, 256, 0, stream>>>(hA, P[6], P[7], P[12], P[13], xbB, hB, N);
    k_msg<64><<<mbl, 512, 0, stream>>>(zge, xbB, src, dstv, w2a, hB, E);

    // ---- layer 3 (cin = 64) ----
    k_edge_prep<64><<<ebl + 65, 256, 0, stream>>>(ea, P[16], P[17], zge, E, ebl, P[18], P[19], w2a);
    k_ln_root<<<nln, 256, 0, stream>>>(hB, P[14], P[15], P[20], P[21], xbA, hA, N);
    k_msg<64><<<mbl, 512, 0, stream>>>(zge, xbA, src, dstv, w2a, hA, E);
    k_ln<<<nln, 256, 0, stream>>>(hA, P[22], P[23], N);

    // ---- fused pool + head ----
    k_pool_head<<<G, 256, 0, stream>>>(hA, batch, fc1w, fc1b, fc2w, fc2b, (float*)d_out, N);
}

// Round 12
// 350.476 us; speedup vs baseline: 1.4157x; 1.4157x over previous
//
#include <hip/hip_runtime.h>
#include <hip/hip_bf16.h>

#define EPSV 1e-5f

typedef __attribute__((ext_vector_type(8))) short bf16x8;
typedef __attribute__((ext_vector_type(16))) float f32x16;

static __device__ __forceinline__ short f2bf(float f) {
    __hip_bfloat16 b = __float2bfloat16(f);
    return __builtin_bit_cast(short, b);
}
static __device__ __forceinline__ float bf2f(short s) {
    unsigned u = ((unsigned)(unsigned short)s) << 16;
    return __builtin_bit_cast(float, u);
}

// Fused role-split: blocks [0,EBL) = edge MLP; blocks [EBL, EBL+65) = w2->w2a repack.
// w2a slab layout: [(c*2+rowg)*512 + l*8 + j] = bf16(w2[h][i*64+o]),
//   o = rowg*32+(l&31), i = c*16+(l>>5)*8+j ; slab 64 = b2.
// zge[e*64 + h] = bf16(relu(b1[h] + ea@w1))
template <int CIN>
__global__ void k_edge_prep(const float* __restrict__ ea, const float* __restrict__ w1,
                            const float* __restrict__ b1, short* __restrict__ zge, int E, int EBL,
                            const float* __restrict__ w2, const float* __restrict__ b2,
                            short* __restrict__ w2a) {
    constexpr int CH = CIN / 16;
    int t = threadIdx.x;
    if ((int)blockIdx.x >= EBL) {
        int h = (int)blockIdx.x - EBL;          // 0..64
        __shared__ float sW[CIN][65];
        const float* srcp = (h < 64) ? (w2 + (size_t)h * (CIN * 64)) : b2;
        for (int f = t; f < CIN * 64; f += 256) sW[f >> 6][f & 63] = srcp[f];
        __syncthreads();
        int l = t & 63, w = t >> 6;
        short* outp = w2a + (size_t)h * (CH * 1024);
        constexpr int SEGW = (CH * 2) / 4 > 0 ? (CH * 2) / 4 : 1;
        #pragma unroll
        for (int q = 0; q < SEGW; ++q) {
            int s = w + q * 4;
            int c = s >> 1, rowg = s & 1;
            int ib = c * 16 + (l >> 5) * 8;
            int o = rowg * 32 + (l & 31);
            union { bf16x8 v; short sh[8]; } ov;
            #pragma unroll
            for (int j = 0; j < 8; ++j) ov.sh[j] = f2bf(sW[ib + j][o]);
            *reinterpret_cast<bf16x8*>(outp + s * 512 + l * 8) = ov.v;
        }
        return;
    }
    __shared__ float sEA[64][17];
    int e0 = blockIdx.x * 64;
    for (int f = t; f < 64 * 16; f += 256) {
        int e = f >> 4, i = f & 15;
        int ge = e0 + e;
        sEA[e][i] = (ge < E) ? ea[(size_t)ge * 16 + i] : 0.f;
    }
    __syncthreads();
    int lane = t & 63, w = t >> 6;
    int ge = e0 + lane;
    union { bf16x8 v[2]; short s[16]; } ov;
    #pragma unroll
    for (int hh = 0; hh < 16; ++hh) {
        int h = w * 16 + hh;
        float acc = b1[h];
        #pragma unroll
        for (int i = 0; i < 16; ++i) acc += sEA[lane][i] * w1[i * 64 + h];
        ov.s[hh] = f2bf(fmaxf(acc, 0.f));
    }
    if (ge < E) {
        short* base = zge + (size_t)ge * 64 + w * 16;
        *reinterpret_cast<bf16x8*>(base) = ov.v[0];
        *reinterpret_cast<bf16x8*>(base + 8) = ov.v[1];
    }
}

// layer-1 fused prep: agg init (root GEMM on x) + x -> bf16
__global__ void k_pre1(const float* __restrict__ x, const float* __restrict__ root,
                       const float* __restrict__ bias, short* __restrict__ xb,
                       float* __restrict__ out, int N) {
    int idx = blockIdx.x * blockDim.x + threadIdx.x;
    int n = idx >> 6, o = idx & 63;
    if (n >= N) return;
    float acc = bias[o];
    #pragma unroll
    for (int i = 0; i < 32; ++i) acc += x[(size_t)n * 32 + i] * root[i * 64 + o];
    out[(size_t)n * 64 + o] = acc;
    if (o < 32) xb[(size_t)n * 32 + o] = f2bf(x[(size_t)n * 32 + o]);
}

// MFMA msg v10: 128-edge tile + x2 h-split; register streaming (round-6 structure,
// the proven ~6 TB/s path), A-fragment reuse across 2 e-groups, 2-buffer X/Y rotation
// with sched_barrier fences; z in padded LDS. 256 threads = 4 waves (rowg x ew).
template <int CIN>
__global__ __launch_bounds__(256, 3) void k_msg(const short* __restrict__ zge,
                                                const short* __restrict__ xb,
                                                const int* __restrict__ src,
                                                const int* __restrict__ dstv,
                                                const short* __restrict__ w2a,
                                                float* __restrict__ agg, int E) {
    constexpr int CH = CIN / 16;
    constexpr int SLAB = CH * 1024;        // shorts per h-slab
    __shared__ char smem[64 * 66 * 4] __attribute__((aligned(16)));  // sT f32 / sZ bf16 overlay
    short* sZ = reinterpret_cast<short*>(smem);        // [128][34] bf16, padded
    float* sT = reinterpret_cast<float*>(smem);        // [64][66] f32 (epilogue reuse)

    int t = threadIdx.x;
    int tile = blockIdx.x >> 1, hb = blockIdx.x & 1;
    int e0 = tile * 128;
    int lane = t & 63, w = t >> 6;
    int rowg = w >> 1;            // o half
    int ew = w & 1;               // 64-edge half
    int kg = lane >> 5, l31 = lane & 31;
    int ec0 = ew * 64 + l31;      // block-local e-col, acc0
    int ec1 = ew * 64 + 32 + l31; // acc1
    int gc0 = min(e0 + ec0, E - 1);
    int gc1 = min(e0 + ec1, E - 1);
    int hbase = hb * 32;
    int clampsl = 31 + hb;        // last valid slab index (relative)

    // B operands: x[src(e)] fragments for the wave's two e-groups, fixed across all h
    int s0 = src[gc0], s1 = src[gc1];
    bf16x8 xB0[CH], xB1[CH];
    #pragma unroll
    for (int c = 0; c < CH; ++c) {
        xB0[c] = *reinterpret_cast<const bf16x8*>(xb + (size_t)s0 * CIN + c * 16 + kg * 8);
        xB1[c] = *reinterpret_cast<const bf16x8*>(xb + (size_t)s1 * CIN + c * 16 + kg * 8);
    }

    // z tile -> LDS: 128 edges x 32 h (this block's h-half), rows padded to 34 shorts
    #pragma unroll
    for (int rr = 0; rr < 2; ++rr) {
        int f = rr * 256 + t;              // 512 units: e = f>>2, seg = f&3
        int e = f >> 2, seg = f & 3;
        int gz = min(e0 + e, E - 1);
        bf16x8 zv = *reinterpret_cast<const bf16x8*>(zge + (size_t)gz * 64 + hbase + seg * 8);
        *reinterpret_cast<bf16x8*>(sZ + e * 34 + seg * 8) = zv;
    }

    f32x16 zero;
    #pragma unroll
    for (int r = 0; r < 16; ++r) zero[r] = 0.f;
    asm volatile("" : "+v"(zero));

    f32x16 acc0 = zero, acc1 = zero;

    const short* ap = w2a + (size_t)hbase * SLAB + rowg * 512 + lane * 8;

    bf16x8 X[CH], Y[CH];
    auto loadA = [&](bf16x8* B, int sl) {
        const short* g = ap + (size_t)min(sl, clampsl) * SLAB;
        #pragma unroll
        for (int c = 0; c < CH; ++c)
            B[c] = *reinterpret_cast<const bf16x8*>(g + c * 1024);
    };
    auto consume = [&](const bf16x8* B, int ci, bool isb2) {
        f32x16 t0 = __builtin_amdgcn_mfma_f32_32x32x16_bf16(B[0], xB0[0], zero, 0, 0, 0);
        f32x16 t1 = __builtin_amdgcn_mfma_f32_32x32x16_bf16(B[0], xB1[0], zero, 0, 0, 0);
        #pragma unroll
        for (int c = 1; c < CH; ++c) {
            t0 = __builtin_amdgcn_mfma_f32_32x32x16_bf16(B[c], xB0[c], t0, 0, 0, 0);
            t1 = __builtin_amdgcn_mfma_f32_32x32x16_bf16(B[c], xB1[c], t1, 0, 0, 0);
        }
        if (!isb2) {
            float z0 = bf2f(sZ[ec0 * 34 + ci]);
            float z1 = bf2f(sZ[ec1 * 34 + ci]);
            #pragma unroll
            for (int r = 0; r < 16; ++r) {
                acc0[r] = fmaf(z0, t0[r], acc0[r]);
                acc1[r] = fmaf(z1, t1[r], acc1[r]);
            }
        } else {
            #pragma unroll
            for (int r = 0; r < 16; ++r) { acc0[r] += t0[r]; acc1[r] += t1[r]; }
        }
    };

    loadA(X, 0); loadA(Y, 1);
    __syncthreads();   // sZ ready

    #pragma unroll 1
    for (int k = 0; k < 16; ++k) {         // slabs 0..31, 2 per iteration
        consume(X, 2 * k, false);  loadA(X, 2 * k + 2);
        __builtin_amdgcn_sched_barrier(0);
        consume(Y, 2 * k + 1, false); loadA(Y, 2 * k + 3);
        __builtin_amdgcn_sched_barrier(0);
    }
    if (hb) consume(X, 32, true);          // b2 slab (z = 1), clamped prefetch holds it

    __syncthreads();   // all sZ reads done before sT overwrite

    // two-pass transpose+scatter: pass p handles block-local e-cols [p*64, p*64+64)
    #pragma unroll
    for (int p = 0; p < 2; ++p) {
        if (ew == p) {
            #pragma unroll
            for (int r = 0; r < 16; ++r) {
                int o = (r & 3) + 8 * (r >> 2) + 4 * kg + 32 * rowg;
                sT[o * 66 + l31] = acc0[r];
                sT[o * 66 + 32 + l31] = acc1[r];
            }
        }
        __syncthreads();
        for (int e = w; e < 64; e += 4) {
            int geo = e0 + p * 64 + e;
            if (geo < E) {
                int d = dstv[geo];
                atomicAdd(&agg[(size_t)d * 64 + lane], sT[lane * 66 + e]);
            }
        }
        __syncthreads();
    }
}

// fused LayerNorm+ReLU -> bf16 (for next msg) AND next layer's root GEMM (agg init).
__global__ void k_ln_root(const float* __restrict__ hin, const float* __restrict__ g,
                          const float* __restrict__ b, const float* __restrict__ root,
                          const float* __restrict__ bias, short* __restrict__ xbout,
                          float* __restrict__ aggnext, int N) {
    __shared__ float sh[4][64];
    int w = threadIdx.x >> 6, lane = threadIdx.x & 63;
    int n = blockIdx.x * 4 + w;
    bool valid = n < N;
    int nc = valid ? n : (N - 1);
    float v = hin[(size_t)nc * 64 + lane];
    float s = v;
    #pragma unroll
    for (int d = 32; d > 0; d >>= 1) s += __shfl_xor(s, d, 64);
    float mean = s * (1.f / 64.f);
    float dv = v - mean;
    float s2 = dv * dv;
    #pragma unroll
    for (int d = 32; d > 0; d >>= 1) s2 += __shfl_xor(s2, d, 64);
    float var = s2 * (1.f / 64.f);
    float o = fmaxf(dv * rsqrtf(var + EPSV) * g[lane] + b[lane], 0.f);
    if (valid) xbout[(size_t)n * 64 + lane] = f2bf(o);
    sh[w][lane] = o;
    __syncthreads();
    float acc = bias[lane];
    #pragma unroll 8
    for (int i = 0; i < 64; ++i) acc = fmaf(sh[w][i], root[i * 64 + lane], acc);
    if (valid) aggnext[(size_t)n * 64 + lane] = acc;
}

// plain LayerNorm+ReLU in place (final layer)
__global__ void k_ln(float* __restrict__ h, const float* __restrict__ g, const float* __restrict__ b, int N) {
    int n = blockIdx.x * 4 + (threadIdx.x >> 6);
    int lane = threadIdx.x & 63;
    if (n >= N) return;
    float v = h[(size_t)n * 64 + lane];
    float s = v;
    #pragma unroll
    for (int d = 32; d > 0; d >>= 1) s += __shfl_xor(s, d, 64);
    float mean = s * (1.f / 64.f);
    float dv = v - mean;
    float s2 = dv * dv;
    #pragma unroll
    for (int d = 32; d > 0; d >>= 1) s2 += __shfl_xor(s2, d, 64);
    float var = s2 * (1.f / 64.f);
    h[(size_t)n * 64 + lane] = fmaxf(dv * rsqrtf(var + EPSV) * g[lane] + b[lane], 0.f);
}

// fused mean-pool (binary search on sorted batch) + MLP head; 4 waves/graph
__global__ void k_pool_head(const float* __restrict__ h, const int* __restrict__ batch,
                            const float* __restrict__ fc1w, const float* __restrict__ fc1b,
                            const float* __restrict__ fc2w, const float* __restrict__ fc2b,
                            float* __restrict__ out, int N) {
    __shared__ float part[4][64];
    __shared__ float sh[64];
    __shared__ float sh2[32];
    int g = blockIdx.x;
    int t = threadIdx.x, lane = t & 63, w = t >> 6;
    int lo = 0, hi = N;
    while (lo < hi) { int m = (lo + hi) >> 1; if (batch[m] < g) lo = m + 1; else hi = m; }
    int s0 = lo;
    hi = N;
    while (lo < hi) { int m = (lo + hi) >> 1; if (batch[m] < g + 1) lo = m + 1; else hi = m; }
    int s1 = lo;
    float s = 0.f;
    for (int n = s0 + w; n < s1; n += 4) s += h[(size_t)n * 64 + lane];
    part[w][lane] = s;
    __syncthreads();
    if (t < 64) {
        float c = fmaxf((float)(s1 - s0), 1.f);
        sh[t] = (part[0][t] + part[1][t] + part[2][t] + part[3][t]) / c;
    }
    __syncthreads();
    if (t < 32) {
        float a = fc1b[t];
        #pragma unroll
        for (int o = 0; o < 64; ++o) a += sh[o] * fc1w[o * 32 + t];
        sh2[t] = fmaxf(a, 0.f);
    }
    __syncthreads();
    if (t == 0) {
        float a = fc2b[0];
        #pragma unroll
        for (int j = 0; j < 32; ++j) a += sh2[j] * fc2w[j];
        out[g] = a;
    }
}

extern "C" void kernel_launch(void* const* d_in, const int* in_sizes, int n_in,
                              void* d_out, int out_size, void* d_ws, size_t ws_size,
                              hipStream_t stream) {
    const float* x     = (const float*)d_in[0];
    const int*   ei    = (const int*)d_in[1];
    const float* ea    = (const float*)d_in[2];
    const int*   batch = (const int*)d_in[3];
    int E = in_sizes[1] / 2;
    int N = in_sizes[3];
    int G = out_size;  // DOUT = 1
    const int* src  = ei;
    const int* dstv = ei + E;

    const float* P[24];
    for (int i = 0; i < 24; ++i) P[i] = (const float*)d_in[4 + i];
    const float* fc1w = (const float*)d_in[28];
    const float* fc1b = (const float*)d_in[29];
    const float* fc2w = (const float*)d_in[30];
    const float* fc2b = (const float*)d_in[31];

    // workspace layout
    float* hA  = (float*)d_ws;                 // N*64 f32
    float* hB  = hA + (size_t)N * 64;          // N*64 f32
    short* zge = (short*)(hB + (size_t)N * 64);// E*64 bf16 (z rows)
    short* xbA = zge + (size_t)E * 64;         // N*64 bf16
    short* xbB = xbA + (size_t)N * 64;         // N*64 bf16
    short* w2a = xbB + (size_t)N * 64;         // 65 slabs * CH*1024 bf16

    int ebl = (E + 63) / 64;
    int mbl = 2 * ((E + 127) / 128);           // 128-edge tiles x 2 h-halves
    int n64 = (N * 64 + 255) / 256;
    int nln = (N + 3) / 4;

    // ---- layer 1 (cin = 32) ----
    k_edge_prep<32><<<ebl + 65, 256, 0, stream>>>(ea, P[0], P[1], zge, E, ebl, P[2], P[3], w2a);
    k_pre1<<<n64, 256, 0, stream>>>(x, P[4], P[5], xbA, hA, N);
    k_msg<32><<<mbl, 256, 0, stream>>>(zge, xbA, src, dstv, w2a, hA, E);

    // ---- layer 2 (cin = 64) ----
    k_edge_prep<64><<<ebl + 65, 256, 0, stream>>>(ea, P[8], P[9], zge, E, ebl, P[10], P[11], w2a);
    k_ln_root<<<nln, 256, 0, stream>>>(hA, P[6], P[7], P[12], P[13], xbB, hB, N);
    k_msg<64><<<mbl, 256, 0, stream>>>(zge, xbB, src, dstv, w2a, hB, E);

    // ---- layer 3 (cin = 64) ----
    k_edge_prep<64><<<ebl + 65, 256, 0, stream>>>(ea, P[16], P[17], zge, E, ebl, P[18], P[19], w2a);
    k_ln_root<<<nln, 256, 0, stream>>>(hB, P[14], P[15], P[20], P[21], xbA, hA, N);
    k_msg<64><<<mbl, 256, 0, stream>>>(zge, xbA, src, dstv, w2a, hA, E);
    k_ln<<<nln, 256, 0, stream>>>(hA, P[22], P[23], N);

    // ---- fused pool + head ----
    k_pool_head<<<G, 256, 0, stream>>>(hA, batch, fc1w, fc1b, fc2w, fc2b, (float*)d_out, N);
}

// Round 13
// 327.845 us; speedup vs baseline: 1.5135x; 1.0690x over previous
//
#include <hip/hip_runtime.h>
#include <hip/hip_bf16.h>

#define EPSV 1e-5f

typedef __attribute__((ext_vector_type(8))) short bf16x8;
typedef __attribute__((ext_vector_type(16))) float f32x16;

static __device__ __forceinline__ short f2bf(float f) {
    __hip_bfloat16 b = __float2bfloat16(f);
    return __builtin_bit_cast(short, b);
}
static __device__ __forceinline__ float bf2f(short s) {
    unsigned u = ((unsigned)(unsigned short)s) << 16;
    return __builtin_bit_cast(float, u);
}

typedef __attribute__((address_space(3))) void lds_t;
typedef const __attribute__((address_space(1))) void gbl_t;
static __device__ __forceinline__ void glds16(const void* g, void* l) {
    __builtin_amdgcn_global_load_lds((gbl_t*)g, (lds_t*)l, 16, 0, 0);
}

// Fused role-split: blocks [0,EBL) = edge MLP; blocks [EBL, EBL+65) = w2->w2a repack.
// w2a slab layout (h-slab = 64 o x CIN i, fragment order):
//   [(c*2+rowg)*512 + l*8 + j] = bf16(w2[h][i*64+o]), o = rowg*32+(l&31),
//   i = c*16+(l>>5)*8+j ; slab 64 = b2.
// zge[e*64 + h] = bf16(relu(b1[h] + ea@w1))
template <int CIN>
__global__ void k_edge_prep(const float* __restrict__ ea, const float* __restrict__ w1,
                            const float* __restrict__ b1, short* __restrict__ zge, int E, int EBL,
                            const float* __restrict__ w2, const float* __restrict__ b2,
                            short* __restrict__ w2a) {
    constexpr int CH = CIN / 16;
    int t = threadIdx.x;
    if ((int)blockIdx.x >= EBL) {
        int h = (int)blockIdx.x - EBL;          // 0..64
        __shared__ float sW[CIN][65];
        const float* srcp = (h < 64) ? (w2 + (size_t)h * (CIN * 64)) : b2;
        for (int f = t; f < CIN * 64; f += 256) sW[f >> 6][f & 63] = srcp[f];
        __syncthreads();
        int l = t & 63, w = t >> 6;
        short* outp = w2a + (size_t)h * (CH * 1024);
        constexpr int SEGW = (CH * 2) / 4 > 0 ? (CH * 2) / 4 : 1;
        #pragma unroll
        for (int q = 0; q < SEGW; ++q) {
            int s = w + q * 4;
            int c = s >> 1, rowg = s & 1;
            int ib = c * 16 + (l >> 5) * 8;
            int o = rowg * 32 + (l & 31);
            union { bf16x8 v; short sh[8]; } ov;
            #pragma unroll
            for (int j = 0; j < 8; ++j) ov.sh[j] = f2bf(sW[ib + j][o]);
            *reinterpret_cast<bf16x8*>(outp + s * 512 + l * 8) = ov.v;
        }
        return;
    }
    __shared__ float sEA[64][17];
    int e0 = blockIdx.x * 64;
    for (int f = t; f < 64 * 16; f += 256) {
        int e = f >> 4, i = f & 15;
        int ge = e0 + e;
        sEA[e][i] = (ge < E) ? ea[(size_t)ge * 16 + i] : 0.f;
    }
    __syncthreads();
    int lane = t & 63, w = t >> 6;
    int ge = e0 + lane;
    union { bf16x8 v[2]; short s[16]; } ov;
    #pragma unroll
    for (int hh = 0; hh < 16; ++hh) {
        int h = w * 16 + hh;
        float acc = b1[h];
        #pragma unroll
        for (int i = 0; i < 16; ++i) acc += sEA[lane][i] * w1[i * 64 + h];
        ov.s[hh] = f2bf(fmaxf(acc, 0.f));
    }
    if (ge < E) {
        short* base = zge + (size_t)ge * 64 + w * 16;
        *reinterpret_cast<bf16x8*>(base) = ov.v[0];
        *reinterpret_cast<bf16x8*>(base + 8) = ov.v[1];
    }
}

// layer-1 fused prep: agg init (root GEMM on x) + x -> bf16
__global__ void k_pre1(const float* __restrict__ x, const float* __restrict__ root,
                       const float* __restrict__ bias, short* __restrict__ xb,
                       float* __restrict__ out, int N) {
    int idx = blockIdx.x * blockDim.x + threadIdx.x;
    int n = idx >> 6, o = idx & 63;
    if (n >= N) return;
    float acc = bias[o];
    #pragma unroll
    for (int i = 0; i < 32; ++i) acc += x[(size_t)n * 32 + i] * root[i * 64 + o];
    out[(size_t)n * 64 + o] = acc;
    if (o < 32) xb[(size_t)n * 32 + o] = f2bf(x[(size_t)n * 32 + o]);
}

// MFMA msg v11 (persistent-weight): block = 1 quadrant (rowg o-half x hb h-half),
// weight quadrant staged ONCE into LDS (~135 KB), then loop over edge tiles with a
// barrier-free ds_read->MFMA inner loop. grid = NG tile-groups x 4 quadrants = 256.
// 8 waves: sh = w>>1 (slab quarter), egp = w&1 (64-edge half; 2 e-groups per wave).
template <int CIN>
__global__ __launch_bounds__(512, 2) void k_msg(const short* __restrict__ zge,
                                                const short* __restrict__ xb,
                                                const int* __restrict__ src,
                                                const int* __restrict__ dstv,
                                                const short* __restrict__ w2a,
                                                float* __restrict__ agg, int E, int NG) {
    constexpr int CH = CIN / 16;
    constexpr int SLAB_FULL = CH * 1024;          // shorts per full h-slab in w2a
    constexpr int QSEG = 512;                      // shorts per (slab, c) quadrant segment
    __shared__ short sQ[33 * CH * QSEG] __attribute__((aligned(16)));  // weight quadrant
    __shared__ char smem2[32 * 132 * 4] __attribute__((aligned(16))); // sZ / sT overlay
    short* sZ = reinterpret_cast<short*>(smem2);   // [128][34] bf16 (8704 B)
    float* sT = reinterpret_cast<float*>(smem2);   // [32][132] f32 (16896 B)

    int t = threadIdx.x;
    int bid = blockIdx.x;
    int grp = bid >> 2;
    int rowg = bid & 1;            // o half
    int hb = (bid >> 1) & 1;       // h half
    int lane = t & 63, w = t >> 6;
    int sh = w >> 1;               // slab quarter 0..3
    int egp = w & 1;               // 64-edge half
    int kg = lane >> 5, l31 = lane & 31;
    int hbase = hb * 32;
    int nsl = 32 + hb;             // local slabs (hb=1 includes b2)
    int sl0 = sh * 8;
    int sl1 = (hb && sh == 3) ? 33 : (sl0 + 8);
    int ec0 = egp * 64 + l31;      // block-local edge cols (two groups per wave)
    int ec1 = egp * 64 + 32 + l31;

    // ---- one-time: stage weight quadrant into LDS (coalesced 16B glds) ----
    for (int f = w; f < nsl * CH; f += 8) {
        int sl = f >> (CH == 4 ? 2 : 1);
        int c = f & (CH - 1);
        glds16(w2a + (size_t)(hbase + sl) * SLAB_FULL + (c * 2 + rowg) * 512 + lane * 8,
               sQ + f * QSEG);
    }

    f32x16 zero;
    #pragma unroll
    for (int r = 0; r < 16; ++r) zero[r] = 0.f;
    asm volatile("" : "+v"(zero));

    int NT = (E + 127) >> 7;
    #pragma unroll 1
    for (int et = grp; et < NT; et += NG) {
        int e0 = et * 128;
        __syncthreads();   // previous scatter done (sT free); 1st iter: glds drain

        // stage z tile: 128 edges x 32 h (this hb half), rows padded to 34 shorts
        {
            int e = t >> 2, seg = t & 3;
            int gz = min(e0 + e, E - 1);
            bf16x8 zv = *reinterpret_cast<const bf16x8*>(zge + (size_t)gz * 64 + hbase + seg * 8);
            *reinterpret_cast<bf16x8*>(sZ + e * 34 + seg * 8) = zv;
        }
        // B operands: x[src(e)] for this wave's two e-groups
        int gc0 = min(e0 + ec0, E - 1), gc1 = min(e0 + ec1, E - 1);
        int s0 = src[gc0], s1 = src[gc1];
        bf16x8 xB0[CH], xB1[CH];
        #pragma unroll
        for (int c = 0; c < CH; ++c) {
            xB0[c] = *reinterpret_cast<const bf16x8*>(xb + (size_t)s0 * CIN + c * 16 + kg * 8);
            xB1[c] = *reinterpret_cast<const bf16x8*>(xb + (size_t)s1 * CIN + c * 16 + kg * 8);
        }
        __syncthreads();   // sZ ready (drains z stores + glds on 1st iter)

        f32x16 acc0 = zero, acc1 = zero;
        #pragma unroll 2
        for (int sl = sl0; sl < sl1; ++sl) {
            const short* qb = sQ + (size_t)sl * (CH * QSEG) + lane * 8;
            bf16x8 a[CH];
            #pragma unroll
            for (int c = 0; c < CH; ++c)
                a[c] = *reinterpret_cast<const bf16x8*>(qb + c * QSEG);
            f32x16 t0 = __builtin_amdgcn_mfma_f32_32x32x16_bf16(a[0], xB0[0], zero, 0, 0, 0);
            f32x16 t1 = __builtin_amdgcn_mfma_f32_32x32x16_bf16(a[0], xB1[0], zero, 0, 0, 0);
            #pragma unroll
            for (int c = 1; c < CH; ++c) {
                t0 = __builtin_amdgcn_mfma_f32_32x32x16_bf16(a[c], xB0[c], t0, 0, 0, 0);
                t1 = __builtin_amdgcn_mfma_f32_32x32x16_bf16(a[c], xB1[c], t1, 0, 0, 0);
            }
            if (hb && sl == 32) {   // b2 slab: z = 1
                #pragma unroll
                for (int r = 0; r < 16; ++r) { acc0[r] += t0[r]; acc1[r] += t1[r]; }
            } else {
                float z0 = bf2f(sZ[ec0 * 34 + sl]);
                float z1 = bf2f(sZ[ec1 * 34 + sl]);
                #pragma unroll
                for (int r = 0; r < 16; ++r) {
                    acc0[r] = fmaf(z0, t0[r], acc0[r]);
                    acc1[r] = fmaf(z1, t1[r], acc1[r]);
                }
            }
        }
        __syncthreads();   // compute done; sZ dead -> sT may be written

        // 4-pass cross-wave (slab-quarter) reduction into sT[32 o][128 e]
        #pragma unroll
        for (int p = 0; p < 4; ++p) {
            if (sh == p) {
                #pragma unroll
                for (int r = 0; r < 16; ++r) {
                    int o32 = (r & 3) + 8 * (r >> 2) + 4 * kg;
                    if (p == 0) {
                        sT[o32 * 132 + ec0] = acc0[r];
                        sT[o32 * 132 + ec1] = acc1[r];
                    } else {
                        sT[o32 * 132 + ec0] += acc0[r];
                        sT[o32 * 132 + ec1] += acc1[r];
                    }
                }
            }
            __syncthreads();
        }

        // coalesced scatter: each 32-thread group writes one edge's 32 contiguous o
        #pragma unroll 1
        for (int f2 = t; f2 < 128 * 32; f2 += 512) {
            int e = f2 >> 5, o32 = f2 & 31;
            int geo = e0 + e;
            if (geo < E) {
                int d = dstv[geo];
                atomicAdd(&agg[(size_t)d * 64 + rowg * 32 + o32], sT[o32 * 132 + e]);
            }
        }
    }
}

// fused LayerNorm+ReLU -> bf16 (for next msg) AND next layer's root GEMM (agg init).
__global__ void k_ln_root(const float* __restrict__ hin, const float* __restrict__ g,
                          const float* __restrict__ b, const float* __restrict__ root,
                          const float* __restrict__ bias, short* __restrict__ xbout,
                          float* __restrict__ aggnext, int N) {
    __shared__ float sh[4][64];
    int w = threadIdx.x >> 6, lane = threadIdx.x & 63;
    int n = blockIdx.x * 4 + w;
    bool valid = n < N;
    int nc = valid ? n : (N - 1);
    float v = hin[(size_t)nc * 64 + lane];
    float s = v;
    #pragma unroll
    for (int d = 32; d > 0; d >>= 1) s += __shfl_xor(s, d, 64);
    float mean = s * (1.f / 64.f);
    float dv = v - mean;
    float s2 = dv * dv;
    #pragma unroll
    for (int d = 32; d > 0; d >>= 1) s2 += __shfl_xor(s2, d, 64);
    float var = s2 * (1.f / 64.f);
    float o = fmaxf(dv * rsqrtf(var + EPSV) * g[lane] + b[lane], 0.f);
    if (valid) xbout[(size_t)n * 64 + lane] = f2bf(o);
    sh[w][lane] = o;
    __syncthreads();
    float acc = bias[lane];
    #pragma unroll 8
    for (int i = 0; i < 64; ++i) acc = fmaf(sh[w][i], root[i * 64 + lane], acc);
    if (valid) aggnext[(size_t)n * 64 + lane] = acc;
}

// plain LayerNorm+ReLU in place (final layer)
__global__ void k_ln(float* __restrict__ h, const float* __restrict__ g, const float* __restrict__ b, int N) {
    int n = blockIdx.x * 4 + (threadIdx.x >> 6);
    int lane = threadIdx.x & 63;
    if (n >= N) return;
    float v = h[(size_t)n * 64 + lane];
    float s = v;
    #pragma unroll
    for (int d = 32; d > 0; d >>= 1) s += __shfl_xor(s, d, 64);
    float mean = s * (1.f / 64.f);
    float dv = v - mean;
    float s2 = dv * dv;
    #pragma unroll
    for (int d = 32; d > 0; d >>= 1) s2 += __shfl_xor(s2, d, 64);
    float var = s2 * (1.f / 64.f);
    h[(size_t)n * 64 + lane] = fmaxf(dv * rsqrtf(var + EPSV) * g[lane] + b[lane], 0.f);
}

// fused mean-pool (binary search on sorted batch) + MLP head; 4 waves/graph
__global__ void k_pool_head(const float* __restrict__ h, const int* __restrict__ batch,
                            const float* __restrict__ fc1w, const float* __restrict__ fc1b,
                            const float* __restrict__ fc2w, const float* __restrict__ fc2b,
                            float* __restrict__ out, int N) {
    __shared__ float part[4][64];
    __shared__ float sh[64];
    __shared__ float sh2[32];
    int g = blockIdx.x;
    int t = threadIdx.x, lane = t & 63, w = t >> 6;
    int lo = 0, hi = N;
    while (lo < hi) { int m = (lo + hi) >> 1; if (batch[m] < g) lo = m + 1; else hi = m; }
    int s0 = lo;
    hi = N;
    while (lo < hi) { int m = (lo + hi) >> 1; if (batch[m] < g + 1) lo = m + 1; else hi = m; }
    int s1 = lo;
    float s = 0.f;
    for (int n = s0 + w; n < s1; n += 4) s += h[(size_t)n * 64 + lane];
    part[w][lane] = s;
    __syncthreads();
    if (t < 64) {
        float c = fmaxf((float)(s1 - s0), 1.f);
        sh[t] = (part[0][t] + part[1][t] + part[2][t] + part[3][t]) / c;
    }
    __syncthreads();
    if (t < 32) {
        float a = fc1b[t];
        #pragma unroll
        for (int o = 0; o < 64; ++o) a += sh[o] * fc1w[o * 32 + t];
        sh2[t] = fmaxf(a, 0.f);
    }
    __syncthreads();
    if (t == 0) {
        float a = fc2b[0];
        #pragma unroll
        for (int j = 0; j < 32; ++j) a += sh2[j] * fc2w[j];
        out[g] = a;
    }
}

extern "C" void kernel_launch(void* const* d_in, const int* in_sizes, int n_in,
                              void* d_out, int out_size, void* d_ws, size_t ws_size,
                              hipStream_t stream) {
    const float* x     = (const float*)d_in[0];
    const int*   ei    = (const int*)d_in[1];
    const float* ea    = (const float*)d_in[2];
    const int*   batch = (const int*)d_in[3];
    int E = in_sizes[1] / 2;
    int N = in_sizes[3];
    int G = out_size;  // DOUT = 1
    const int* src  = ei;
    const int* dstv = ei + E;

    const float* P[24];
    for (int i = 0; i < 24; ++i) P[i] = (const float*)d_in[4 + i];
    const float* fc1w = (const float*)d_in[28];
    const float* fc1b = (const float*)d_in[29];
    const float* fc2w = (const float*)d_in[30];
    const float* fc2b = (const float*)d_in[31];

    // workspace layout
    float* hA  = (float*)d_ws;                 // N*64 f32
    float* hB  = hA + (size_t)N * 64;          // N*64 f32
    short* zge = (short*)(hB + (size_t)N * 64);// E*64 bf16 (z rows)
    short* xbA = zge + (size_t)E * 64;         // N*64 bf16
    short* xbB = xbA + (size_t)N * 64;         // N*64 bf16
    short* w2a = xbB + (size_t)N * 64;         // 65 slabs * CH*1024 bf16

    int ebl = (E + 63) / 64;
    int n64 = (N * 64 + 255) / 256;
    int nln = (N + 3) / 4;
    const int NG = 64;                          // tile groups; grid = NG*4 = 256 = 1/CU

    // ---- layer 1 (cin = 32) ----
    k_edge_prep<32><<<ebl + 65, 256, 0, stream>>>(ea, P[0], P[1], zge, E, ebl, P[2], P[3], w2a);
    k_pre1<<<n64, 256, 0, stream>>>(x, P[4], P[5], xbA, hA, N);
    k_msg<32><<<NG * 4, 512, 0, stream>>>(zge, xbA, src, dstv, w2a, hA, E, NG);

    // ---- layer 2 (cin = 64) ----
    k_edge_prep<64><<<ebl + 65, 256, 0, stream>>>(ea, P[8], P[9], zge, E, ebl, P[10], P[11], w2a);
    k_ln_root<<<nln, 256, 0, stream>>>(hA, P[6], P[7], P[12], P[13], xbB, hB, N);
    k_msg<64><<<NG * 4, 512, 0, stream>>>(zge, xbB, src, dstv, w2a, hB, E, NG);

    // ---- layer 3 (cin = 64) ----
    k_edge_prep<64><<<ebl + 65, 256, 0, stream>>>(ea, P[16], P[17], zge, E, ebl, P[18], P[19], w2a);
    k_ln_root<<<nln, 256, 0, stream>>>(hB, P[14], P[15], P[20], P[21], xbA, hA, N);
    k_msg<64><<<NG * 4, 512, 0, stream>>>(zge, xbA, src, dstv, w2a, hA, E, NG);
    k_ln<<<nln, 256, 0, stream>>>(hA, P[22], P[23], N);

    // ---- fused pool + head ----
    k_pool_head<<<G, 256, 0, stream>>>(hA, batch, fc1w, fc1b, fc2w, fc2b, (float*)d_out, N);
}

// Round 14
// 303.953 us; speedup vs baseline: 1.6324x; 1.0786x over previous
//
#include <hip/hip_runtime.h>
#include <hip/hip_bf16.h>

#define EPSV 1e-5f

typedef __attribute__((ext_vector_type(8))) short bf16x8;
typedef __attribute__((ext_vector_type(16))) float f32x16;

static __device__ __forceinline__ short f2bf(float f) {
    __hip_bfloat16 b = __float2bfloat16(f);
    return __builtin_bit_cast(short, b);
}
static __device__ __forceinline__ float bf2f(short s) {
    unsigned u = ((unsigned)(unsigned short)s) << 16;
    return __builtin_bit_cast(float, u);
}

// Fused role-split: blocks [0,EBL) = edge MLP; blocks [EBL, EBL+65) = w2->w2a repack.
// w2a slab layout: [(c*2+rowg)*512 + l*8 + j] = bf16(w2[h][i*64+o]),
//   o = rowg*32+(l&31), i = c*16+(l>>5)*8+j ; slab 64 = b2.
// zge[e*64 + h] = bf16(relu(b1[h] + ea@w1))
template <int CIN>
__global__ void k_edge_prep(const float* __restrict__ ea, const float* __restrict__ w1,
                            const float* __restrict__ b1, short* __restrict__ zge, int E, int EBL,
                            const float* __restrict__ w2, const float* __restrict__ b2,
                            short* __restrict__ w2a) {
    constexpr int CH = CIN / 16;
    int t = threadIdx.x;
    if ((int)blockIdx.x >= EBL) {
        int h = (int)blockIdx.x - EBL;          // 0..64
        __shared__ float sW[CIN][65];
        const float* srcp = (h < 64) ? (w2 + (size_t)h * (CIN * 64)) : b2;
        for (int f = t; f < CIN * 64; f += 256) sW[f >> 6][f & 63] = srcp[f];
        __syncthreads();
        int l = t & 63, w = t >> 6;
        short* outp = w2a + (size_t)h * (CH * 1024);
        constexpr int SEGW = (CH * 2) / 4 > 0 ? (CH * 2) / 4 : 1;
        #pragma unroll
        for (int q = 0; q < SEGW; ++q) {
            int s = w + q * 4;
            int c = s >> 1, rowg = s & 1;
            int ib = c * 16 + (l >> 5) * 8;
            int o = rowg * 32 + (l & 31);
            union { bf16x8 v; short sh[8]; } ov;
            #pragma unroll
            for (int j = 0; j < 8; ++j) ov.sh[j] = f2bf(sW[ib + j][o]);
            *reinterpret_cast<bf16x8*>(outp + s * 512 + l * 8) = ov.v;
        }
        return;
    }
    __shared__ float sEA[64][17];
    int e0 = blockIdx.x * 64;
    for (int f = t; f < 64 * 16; f += 256) {
        int e = f >> 4, i = f & 15;
        int ge = e0 + e;
        sEA[e][i] = (ge < E) ? ea[(size_t)ge * 16 + i] : 0.f;
    }
    __syncthreads();
    int lane = t & 63, w = t >> 6;
    int ge = e0 + lane;
    union { bf16x8 v[2]; short s[16]; } ov;
    #pragma unroll
    for (int hh = 0; hh < 16; ++hh) {
        int h = w * 16 + hh;
        float acc = b1[h];
        #pragma unroll
        for (int i = 0; i < 16; ++i) acc += sEA[lane][i] * w1[i * 64 + h];
        ov.s[hh] = f2bf(fmaxf(acc, 0.f));
    }
    if (ge < E) {
        short* base = zge + (size_t)ge * 64 + w * 16;
        *reinterpret_cast<bf16x8*>(base) = ov.v[0];
        *reinterpret_cast<bf16x8*>(base + 8) = ov.v[1];
    }
}

// layer-1 fused prep: agg init (root GEMM on x) + x -> bf16
__global__ void k_pre1(const float* __restrict__ x, const float* __restrict__ root,
                       const float* __restrict__ bias, short* __restrict__ xb,
                       float* __restrict__ out, int N) {
    int idx = blockIdx.x * blockDim.x + threadIdx.x;
    int n = idx >> 6, o = idx & 63;
    if (n >= N) return;
    float acc = bias[o];
    #pragma unroll
    for (int i = 0; i < 32; ++i) acc += x[(size_t)n * 32 + i] * root[i * 64 + o];
    out[(size_t)n * 64 + o] = acc;
    if (o < 32) xb[(size_t)n * 32 + o] = f2bf(x[(size_t)n * 32 + o]);
}

// MFMA msg v12: plain register-streaming loop (round-6 discipline: NO fences, NO manual
// dbuf -- compiler + 12 waves/CU overlap), 128-edge tile + x2 h-split, A-fragment
// reused across 2 e-groups (halves issued VMEM). z in padded LDS with synthetic
// 1.0 column at index 32 so the b2 slab needs no branch.
template <int CIN>
__global__ __launch_bounds__(256, 3) void k_msg(const short* __restrict__ zge,
                                                const short* __restrict__ xb,
                                                const int* __restrict__ src,
                                                const int* __restrict__ dstv,
                                                const short* __restrict__ w2a,
                                                float* __restrict__ agg, int E) {
    constexpr int CH = CIN / 16;
    constexpr int SLAB = CH * 1024;        // shorts per full h-slab
    __shared__ char smem[64 * 66 * 4] __attribute__((aligned(16)));
    short* sZ = reinterpret_cast<short*>(smem);        // [128][34] bf16, padded
    float* sT = reinterpret_cast<float*>(smem);        // [64][66] f32 (epilogue reuse)

    int t = threadIdx.x;
    int tile = blockIdx.x >> 1, hb = blockIdx.x & 1;
    int e0 = tile * 128;
    int lane = t & 63, w = t >> 6;
    int rowg = w >> 1;            // o half
    int ew = w & 1;               // 64-edge half
    int kg = lane >> 5, l31 = lane & 31;
    int ec0 = ew * 64 + l31;      // block-local e-col, acc0
    int ec1 = ew * 64 + 32 + l31; // acc1
    int gc0 = min(e0 + ec0, E - 1);
    int gc1 = min(e0 + ec1, E - 1);
    int hbase = hb * 32;
    int nsl = 32 + hb;            // slabs this block (hb=1 appends b2, z=1 column)

    // B operands: x[src(e)] fragments for the wave's two e-groups, fixed across all h
    int s0 = src[gc0], s1 = src[gc1];
    bf16x8 xB0[CH], xB1[CH];
    #pragma unroll
    for (int c = 0; c < CH; ++c) {
        xB0[c] = *reinterpret_cast<const bf16x8*>(xb + (size_t)s0 * CIN + c * 16 + kg * 8);
        xB1[c] = *reinterpret_cast<const bf16x8*>(xb + (size_t)s1 * CIN + c * 16 + kg * 8);
    }

    // z tile -> LDS: 128 edges x 32 h (this hb half), rows padded to 34 shorts;
    // column 32 = synthetic z = 1.0 (for the b2 slab when hb = 1)
    #pragma unroll
    for (int rr = 0; rr < 2; ++rr) {
        int f = rr * 256 + t;              // 512 units: e = f>>2, seg = f&3
        int e = f >> 2, seg = f & 3;
        int gz = min(e0 + e, E - 1);
        bf16x8 zv = *reinterpret_cast<const bf16x8*>(zge + (size_t)gz * 64 + hbase + seg * 8);
        *reinterpret_cast<bf16x8*>(sZ + e * 34 + seg * 8) = zv;
    }
    if (t < 128) sZ[t * 34 + 32] = (short)0x3F80;   // bf16(1.0)

    f32x16 zero;
    #pragma unroll
    for (int r = 0; r < 16; ++r) zero[r] = 0.f;
    asm volatile("" : "+v"(zero));

    f32x16 acc0 = zero, acc1 = zero;
    const short* ap = w2a + (size_t)hbase * SLAB + rowg * 512 + lane * 8;

    __syncthreads();   // sZ ready

    #pragma unroll 2
    for (int sl = 0; sl < nsl; ++sl) {
        const short* g = ap + (size_t)sl * SLAB;
        bf16x8 a[CH];
        #pragma unroll
        for (int c = 0; c < CH; ++c)
            a[c] = *reinterpret_cast<const bf16x8*>(g + c * 1024);
        f32x16 t0 = __builtin_amdgcn_mfma_f32_32x32x16_bf16(a[0], xB0[0], zero, 0, 0, 0);
        f32x16 t1 = __builtin_amdgcn_mfma_f32_32x32x16_bf16(a[0], xB1[0], zero, 0, 0, 0);
        #pragma unroll
        for (int c = 1; c < CH; ++c) {
            t0 = __builtin_amdgcn_mfma_f32_32x32x16_bf16(a[c], xB0[c], t0, 0, 0, 0);
            t1 = __builtin_amdgcn_mfma_f32_32x32x16_bf16(a[c], xB1[c], t1, 0, 0, 0);
        }
        float z0 = bf2f(sZ[ec0 * 34 + sl]);
        float z1 = bf2f(sZ[ec1 * 34 + sl]);
        #pragma unroll
        for (int r = 0; r < 16; ++r) {
            acc0[r] = fmaf(z0, t0[r], acc0[r]);
            acc1[r] = fmaf(z1, t1[r], acc1[r]);
        }
    }

    __syncthreads();   // all sZ reads done before sT overwrite

    // two-pass transpose+scatter: pass p handles block-local e-cols [p*64, p*64+64)
    #pragma unroll
    for (int p = 0; p < 2; ++p) {
        if (ew == p) {
            #pragma unroll
            for (int r = 0; r < 16; ++r) {
                int o = (r & 3) + 8 * (r >> 2) + 4 * kg + 32 * rowg;
                sT[o * 66 + l31] = acc0[r];
                sT[o * 66 + 32 + l31] = acc1[r];
            }
        }
        __syncthreads();
        for (int e = w; e < 64; e += 4) {
            int geo = e0 + p * 64 + e;
            if (geo < E) {
                int d = dstv[geo];
                atomicAdd(&agg[(size_t)d * 64 + lane], sT[lane * 66 + e]);
            }
        }
        __syncthreads();
    }
}

// fused LayerNorm+ReLU -> bf16 (for next msg) AND next layer's root GEMM (agg init).
__global__ void k_ln_root(const float* __restrict__ hin, const float* __restrict__ g,
                          const float* __restrict__ b, const float* __restrict__ root,
                          const float* __restrict__ bias, short* __restrict__ xbout,
                          float* __restrict__ aggnext, int N) {
    __shared__ float sh[4][64];
    int w = threadIdx.x >> 6, lane = threadIdx.x & 63;
    int n = blockIdx.x * 4 + w;
    bool valid = n < N;
    int nc = valid ? n : (N - 1);
    float v = hin[(size_t)nc * 64 + lane];
    float s = v;
    #pragma unroll
    for (int d = 32; d > 0; d >>= 1) s += __shfl_xor(s, d, 64);
    float mean = s * (1.f / 64.f);
    float dv = v - mean;
    float s2 = dv * dv;
    #pragma unroll
    for (int d = 32; d > 0; d >>= 1) s2 += __shfl_xor(s2, d, 64);
    float var = s2 * (1.f / 64.f);
    float o = fmaxf(dv * rsqrtf(var + EPSV) * g[lane] + b[lane], 0.f);
    if (valid) xbout[(size_t)n * 64 + lane] = f2bf(o);
    sh[w][lane] = o;
    __syncthreads();
    float acc = bias[lane];
    #pragma unroll 8
    for (int i = 0; i < 64; ++i) acc = fmaf(sh[w][i], root[i * 64 + lane], acc);
    if (valid) aggnext[(size_t)n * 64 + lane] = acc;
}

// plain LayerNorm+ReLU in place (final layer)
__global__ void k_ln(float* __restrict__ h, const float* __restrict__ g, const float* __restrict__ b, int N) {
    int n = blockIdx.x * 4 + (threadIdx.x >> 6);
    int lane = threadIdx.x & 63;
    if (n >= N) return;
    float v = h[(size_t)n * 64 + lane];
    float s = v;
    #pragma unroll
    for (int d = 32; d > 0; d >>= 1) s += __shfl_xor(s, d, 64);
    float mean = s * (1.f / 64.f);
    float dv = v - mean;
    float s2 = dv * dv;
    #pragma unroll
    for (int d = 32; d > 0; d >>= 1) s2 += __shfl_xor(s2, d, 64);
    float var = s2 * (1.f / 64.f);
    h[(size_t)n * 64 + lane] = fmaxf(dv * rsqrtf(var + EPSV) * g[lane] + b[lane], 0.f);
}

// fused mean-pool (binary search on sorted batch) + MLP head; 4 waves/graph
__global__ void k_pool_head(const float* __restrict__ h, const int* __restrict__ batch,
                            const float* __restrict__ fc1w, const float* __restrict__ fc1b,
                            const float* __restrict__ fc2w, const float* __restrict__ fc2b,
                            float* __restrict__ out, int N) {
    __shared__ float part[4][64];
    __shared__ float sh[64];
    __shared__ float sh2[32];
    int g = blockIdx.x;
    int t = threadIdx.x, lane = t & 63, w = t >> 6;
    int lo = 0, hi = N;
    while (lo < hi) { int m = (lo + hi) >> 1; if (batch[m] < g) lo = m + 1; else hi = m; }
    int s0 = lo;
    hi = N;
    while (lo < hi) { int m = (lo + hi) >> 1; if (batch[m] < g + 1) lo = m + 1; else hi = m; }
    int s1 = lo;
    float s = 0.f;
    for (int n = s0 + w; n < s1; n += 4) s += h[(size_t)n * 64 + lane];
    part[w][lane] = s;
    __syncthreads();
    if (t < 64) {
        float c = fmaxf((float)(s1 - s0), 1.f);
        sh[t] = (part[0][t] + part[1][t] + part[2][t] + part[3][t]) / c;
    }
    __syncthreads();
    if (t < 32) {
        float a = fc1b[t];
        #pragma unroll
        for (int o = 0; o < 64; ++o) a += sh[o] * fc1w[o * 32 + t];
        sh2[t] = fmaxf(a, 0.f);
    }
    __syncthreads();
    if (t == 0) {
        float a = fc2b[0];
        #pragma unroll
        for (int j = 0; j < 32; ++j) a += sh2[j] * fc2w[j];
        out[g] = a;
    }
}

extern "C" void kernel_launch(void* const* d_in, const int* in_sizes, int n_in,
                              void* d_out, int out_size, void* d_ws, size_t ws_size,
                              hipStream_t stream) {
    const float* x     = (const float*)d_in[0];
    const int*   ei    = (const int*)d_in[1];
    const float* ea    = (const float*)d_in[2];
    const int*   batch = (const int*)d_in[3];
    int E = in_sizes[1] / 2;
    int N = in_sizes[3];
    int G = out_size;  // DOUT = 1
    const int* src  = ei;
    const int* dstv = ei + E;

    const float* P[24];
    for (int i = 0; i < 24; ++i) P[i] = (const float*)d_in[4 + i];
    const float* fc1w = (const float*)d_in[28];
    const float* fc1b = (const float*)d_in[29];
    const float* fc2w = (const float*)d_in[30];
    const float* fc2b = (const float*)d_in[31];

    // workspace layout
    float* hA  = (float*)d_ws;                 // N*64 f32
    float* hB  = hA + (size_t)N * 64;          // N*64 f32
    short* zge = (short*)(hB + (size_t)N * 64);// E*64 bf16 (z rows)
    short* xbA = zge + (size_t)E * 64;         // N*64 bf16
    short* xbB = xbA + (size_t)N * 64;         // N*64 bf16
    short* w2a = xbB + (size_t)N * 64;         // 65 slabs * CH*1024 bf16

    int ebl = (E + 63) / 64;
    int mbl = 2 * ((E + 127) / 128);           // 128-edge tiles x 2 h-halves
    int n64 = (N * 64 + 255) / 256;
    int nln = (N + 3) / 4;

    // ---- layer 1 (cin = 32) ----
    k_edge_prep<32><<<ebl + 65, 256, 0, stream>>>(ea, P[0], P[1], zge, E, ebl, P[2], P[3], w2a);
    k_pre1<<<n64, 256, 0, stream>>>(x, P[4], P[5], xbA, hA, N);
    k_msg<32><<<mbl, 256, 0, stream>>>(zge, xbA, src, dstv, w2a, hA, E);

    // ---- layer 2 (cin = 64) ----
    k_edge_prep<64><<<ebl + 65, 256, 0, stream>>>(ea, P[8], P[9], zge, E, ebl, P[10], P[11], w2a);
    k_ln_root<<<nln, 256, 0, stream>>>(hA, P[6], P[7], P[12], P[13], xbB, hB, N);
    k_msg<64><<<mbl, 256, 0, stream>>>(zge, xbB, src, dstv, w2a, hB, E);

    // ---- layer 3 (cin = 64) ----
    k_edge_prep<64><<<ebl + 65, 256, 0, stream>>>(ea, P[16], P[17], zge, E, ebl, P[18], P[19], w2a);
    k_ln_root<<<nln, 256, 0, stream>>>(hB, P[14], P[15], P[20], P[21], xbA, hA, N);
    k_msg<64><<<mbl, 256, 0, stream>>>(zge, xbA, src, dstv, w2a, hA, E);
    k_ln<<<nln, 256, 0, stream>>>(hA, P[22], P[23], N);

    // ---- fused pool + head ----
    k_pool_head<<<G, 256, 0, stream>>>(hA, batch, fc1w, fc1b, fc2w, fc2b, (float*)d_out, N);
}